// Round 1
// baseline (267.049 us; speedup 1.0000x reference)
//
#include <hip/hip_runtime.h>
#include <math.h>

#define BATCH 4096
#define NPTS  2048
#define THREADS 256

typedef float f32x4 __attribute__((ext_vector_type(4)));

__device__ __forceinline__ f32x4 ntload(const f32x4* p) {
    return __builtin_nontemporal_load(p);
}

// accumulate one point: h[c*3+d] += src_c * (m * tgt_d)
#define ACC(sx, sy, sz, tx, ty, tz, mm) do {                                   \
    float d0 = (mm) * (tx), d1 = (mm) * (ty), d2 = (mm) * (tz);                \
    h[0] = fmaf((sx), d0, h[0]); h[1] = fmaf((sx), d1, h[1]); h[2] = fmaf((sx), d2, h[2]); \
    h[3] = fmaf((sy), d0, h[3]); h[4] = fmaf((sy), d1, h[4]); h[5] = fmaf((sy), d2, h[5]); \
    h[6] = fmaf((sz), d0, h[6]); h[7] = fmaf((sz), d1, h[7]); h[8] = fmaf((sz), d2, h[8]); \
} while (0)

// Fused kernel: one block per batch.
//  Phase 1 (all 256 threads): H = src^T diag(mask) tgt, streamed NT loads
//    (224 B/thread in one burst), wave butterfly + LDS cross-wave reduce.
//  Phase 2 (thread 0 only): fp64 Jacobi eigensolve of H^T H + Kabsch rotation,
//    written straight to out. Fusing removes the 64-wave solve_kernel launch
//    (latency-bound, fully exposed after the reduce) and the H round-trip
//    through d_ws; solve tails overlap with other blocks' memory phases.
__global__ __launch_bounds__(THREADS, 4)
void fused_kernel(const float* __restrict__ src, const float* __restrict__ tgt,
                  const float* __restrict__ mask, float* __restrict__ out)
{
    const int b   = blockIdx.x;
    const int t   = threadIdx.x;           // group A: t, group B: t+256
    const f32x4* s4 = (const f32x4*)(src  + (size_t)b * (NPTS * 3));
    const f32x4* t4 = (const f32x4*)(tgt  + (size_t)b * (NPTS * 3));
    const f32x4* m4 = (const f32x4*)(mask + (size_t)b * NPTS);

    // ---- one burst: 14 independent NT loads ----
    f32x4 m0  = ntload(&m4[t]);
    f32x4 m1  = ntload(&m4[t + 256]);
    f32x4 sa0 = ntload(&s4[3 * t + 0]);
    f32x4 sb0 = ntload(&s4[3 * t + 1]);
    f32x4 sc0 = ntload(&s4[3 * t + 2]);
    f32x4 ta0 = ntload(&t4[3 * t + 0]);
    f32x4 tb0 = ntload(&t4[3 * t + 1]);
    f32x4 tc0 = ntload(&t4[3 * t + 2]);
    f32x4 sa1 = ntload(&s4[3 * (t + 256) + 0]);
    f32x4 sb1 = ntload(&s4[3 * (t + 256) + 1]);
    f32x4 sc1 = ntload(&s4[3 * (t + 256) + 2]);
    f32x4 ta1 = ntload(&t4[3 * (t + 256) + 0]);
    f32x4 tb1 = ntload(&t4[3 * (t + 256) + 1]);
    f32x4 tc1 = ntload(&t4[3 * (t + 256) + 2]);

    float h[9] = {0.f, 0.f, 0.f, 0.f, 0.f, 0.f, 0.f, 0.f, 0.f};
    ACC(sa0.x, sa0.y, sa0.z, ta0.x, ta0.y, ta0.z, m0.x);
    ACC(sa0.w, sb0.x, sb0.y, ta0.w, tb0.x, tb0.y, m0.y);
    ACC(sb0.z, sb0.w, sc0.x, tb0.z, tb0.w, tc0.x, m0.z);
    ACC(sc0.y, sc0.z, sc0.w, tc0.y, tc0.z, tc0.w, m0.w);
    ACC(sa1.x, sa1.y, sa1.z, ta1.x, ta1.y, ta1.z, m1.x);
    ACC(sa1.w, sb1.x, sb1.y, ta1.w, tb1.x, tb1.y, m1.y);
    ACC(sb1.z, sb1.w, sc1.x, tb1.z, tb1.w, tc1.x, m1.z);
    ACC(sc1.y, sc1.z, sc1.w, tc1.y, tc1.z, tc1.w, m1.w);

    // wave-64 butterfly reduction of the 9 accumulators
#pragma unroll
    for (int off = 32; off > 0; off >>= 1) {
#pragma unroll
        for (int i = 0; i < 9; ++i) h[i] += __shfl_down(h[i], off);
    }

    __shared__ float shred[THREADS / 64][9];
    const int wid  = t >> 6;
    const int lane = t & 63;
    if (lane == 0) {
#pragma unroll
        for (int i = 0; i < 9; ++i) shred[wid][i] = h[i];
    }
    __syncthreads();

    if (t != 0) return;

    // ---- Phase 2: single-thread fp64 Kabsch solve for this batch ----
    double H[3][3];
#pragma unroll
    for (int i = 0; i < 9; ++i)
        H[i / 3][i % 3] = (double)(shred[0][i] + shred[1][i] +
                                   shred[2][i] + shred[3][i]);

    double A[3][3];
#pragma unroll
    for (int i = 0; i < 3; ++i)
#pragma unroll
        for (int j = 0; j < 3; ++j)
            A[i][j] = H[0][i] * H[0][j] + H[1][i] * H[1][j] + H[2][i] * H[2][j];

    double V[3][3] = {{1, 0, 0}, {0, 1, 0}, {0, 0, 1}};

    const int pq[3][3] = {{0, 1, 2}, {0, 2, 1}, {1, 2, 0}};
    for (int sweep = 0; sweep < 6; ++sweep) {
#pragma unroll
        for (int r = 0; r < 3; ++r) {
            const int p = pq[r][0], q = pq[r][1], k = pq[r][2];
            double apq = A[p][q];
            if (fabs(apq) > 1e-300) {
                double theta = (A[q][q] - A[p][p]) / (2.0 * apq);
                double tt = 1.0 / (fabs(theta) + sqrt(theta * theta + 1.0));
                if (theta < 0.0) tt = -tt;
                double c = 1.0 / sqrt(tt * tt + 1.0);
                double s = tt * c;
                double app = A[p][p], aqq = A[q][q];
                A[p][p] = app - tt * apq;
                A[q][q] = aqq + tt * apq;
                A[p][q] = A[q][p] = 0.0;
                double akp = A[k][p], akq = A[k][q];
                A[k][p] = A[p][k] = c * akp - s * akq;
                A[k][q] = A[q][k] = s * akp + c * akq;
#pragma unroll
                for (int i = 0; i < 3; ++i) {
                    double vip = V[i][p], viq = V[i][q];
                    V[i][p] = c * vip - s * viq;
                    V[i][q] = s * vip + c * viq;
                }
            }
        }
    }

    int i0 = 0;
    if (A[1][1] > A[i0][i0]) i0 = 1;
    if (A[2][2] > A[i0][i0]) i0 = 2;
    const int ca = (i0 + 1) % 3, cb = (i0 + 2) % 3;
    const int i1 = (A[ca][ca] >= A[cb][cb]) ? ca : cb;

    double v0[3], v1[3];
#pragma unroll
    for (int i = 0; i < 3; ++i) { v0[i] = V[i][i0]; v1[i] = V[i][i1]; }

    double b0[3], b1[3];
#pragma unroll
    for (int r = 0; r < 3; ++r) {
        b0[r] = H[r][0] * v0[0] + H[r][1] * v0[1] + H[r][2] * v0[2];
        b1[r] = H[r][0] * v1[0] + H[r][1] * v1[1] + H[r][2] * v1[2];
    }
    double n0 = b0[0] * b0[0] + b0[1] * b0[1] + b0[2] * b0[2];
    double inv0 = 1.0 / sqrt(fmax(n0, 1e-300));
    double u0[3] = {b0[0] * inv0, b0[1] * inv0, b0[2] * inv0};
    double d01 = u0[0] * b1[0] + u0[1] * b1[1] + u0[2] * b1[2];
    double w[3] = {b1[0] - d01 * u0[0], b1[1] - d01 * u0[1], b1[2] - d01 * u0[2]};
    double nw = w[0] * w[0] + w[1] * w[1] + w[2] * w[2];
    double inv1 = 1.0 / sqrt(fmax(nw, 1e-300));
    double u1[3] = {w[0] * inv1, w[1] * inv1, w[2] * inv1};
    double u2[3] = {u0[1] * u1[2] - u0[2] * u1[1],
                    u0[2] * u1[0] - u0[0] * u1[2],
                    u0[0] * u1[1] - u0[1] * u1[0]};
    double vc2[3] = {v0[1] * v1[2] - v0[2] * v1[1],
                     v0[2] * v1[0] - v0[0] * v1[2],
                     v0[0] * v1[1] - v0[1] * v1[0]};

    float* o = out + (size_t)b * 9;
#pragma unroll
    for (int r = 0; r < 3; ++r)
#pragma unroll
        for (int c = 0; c < 3; ++c)
            o[r * 3 + c] = (float)(v0[r] * u0[c] + v1[r] * u1[c] + vc2[r] * u2[c]);
}

extern "C" void kernel_launch(void* const* d_in, const int* in_sizes, int n_in,
                              void* d_out, int out_size, void* d_ws, size_t ws_size,
                              hipStream_t stream) {
    const float* src  = (const float*)d_in[0];
    const float* tgt  = (const float*)d_in[1];
    // d_in[2] (kpt_src_mask) is unused by the reference
    const float* mask = (const float*)d_in[3];
    float* out = (float*)d_out;

    fused_kernel<<<BATCH, THREADS, 0, stream>>>(src, tgt, mask, out);
}

// Round 2
// 246.907 us; speedup vs baseline: 1.0816x; 1.0816x over previous
//
#include <hip/hip_runtime.h>
#include <math.h>

#define BATCH 4096
#define NPTS  2048
#define THREADS 256

typedef float f32x4 __attribute__((ext_vector_type(4)));

__device__ __forceinline__ f32x4 ntload(const f32x4* p) {
    return __builtin_nontemporal_load(p);
}

// accumulate one point: h[c*3+d] += src_c * (m * tgt_d)
#define ACC(sx, sy, sz, tx, ty, tz, mm) do {                                   \
    float d0 = (mm) * (tx), d1 = (mm) * (ty), d2 = (mm) * (tz);                \
    h[0] = fmaf((sx), d0, h[0]); h[1] = fmaf((sx), d1, h[1]); h[2] = fmaf((sx), d2, h[2]); \
    h[3] = fmaf((sy), d0, h[3]); h[4] = fmaf((sy), d1, h[4]); h[5] = fmaf((sy), d2, h[5]); \
    h[6] = fmaf((sz), d0, h[6]); h[7] = fmaf((sz), d1, h[7]); h[8] = fmaf((sz), d2, h[8]); \
} while (0)

// Fused kernel: one block per batch.
//  Phase 1 (all 256 threads): H = src^T diag(mask) tgt, streamed NT loads.
//  Phase 2 (thread 0 only): fp64 Jacobi eigensolve of H^T H + Kabsch rotation.
//  CRITICAL: the solve must contain NO runtime-indexed arrays. Round-1's
//  V[i][i0]/A[ca][ca] extraction forced V,A into per-thread LDS slices
//  (LDS_Block_Size ballooned to 18944 B, VGPR collapsed to 36, +2 MB spill
//  writes) and the dependent chain ran at LDS latency -> 82 us. The column
//  extraction below is pure value-selects (cndmask), so SROA keeps all solve
//  state in VGPRs.
__global__ __launch_bounds__(THREADS, 4)
void fused_kernel(const float* __restrict__ src, const float* __restrict__ tgt,
                  const float* __restrict__ mask, float* __restrict__ out)
{
    const int b   = blockIdx.x;
    const int t   = threadIdx.x;           // group A: t, group B: t+256
    const f32x4* s4 = (const f32x4*)(src  + (size_t)b * (NPTS * 3));
    const f32x4* t4 = (const f32x4*)(tgt  + (size_t)b * (NPTS * 3));
    const f32x4* m4 = (const f32x4*)(mask + (size_t)b * NPTS);

    // ---- one burst: 14 independent NT loads ----
    f32x4 m0  = ntload(&m4[t]);
    f32x4 m1  = ntload(&m4[t + 256]);
    f32x4 sa0 = ntload(&s4[3 * t + 0]);
    f32x4 sb0 = ntload(&s4[3 * t + 1]);
    f32x4 sc0 = ntload(&s4[3 * t + 2]);
    f32x4 ta0 = ntload(&t4[3 * t + 0]);
    f32x4 tb0 = ntload(&t4[3 * t + 1]);
    f32x4 tc0 = ntload(&t4[3 * t + 2]);
    f32x4 sa1 = ntload(&s4[3 * (t + 256) + 0]);
    f32x4 sb1 = ntload(&s4[3 * (t + 256) + 1]);
    f32x4 sc1 = ntload(&s4[3 * (t + 256) + 2]);
    f32x4 ta1 = ntload(&t4[3 * (t + 256) + 0]);
    f32x4 tb1 = ntload(&t4[3 * (t + 256) + 1]);
    f32x4 tc1 = ntload(&t4[3 * (t + 256) + 2]);

    float h[9] = {0.f, 0.f, 0.f, 0.f, 0.f, 0.f, 0.f, 0.f, 0.f};
    ACC(sa0.x, sa0.y, sa0.z, ta0.x, ta0.y, ta0.z, m0.x);
    ACC(sa0.w, sb0.x, sb0.y, ta0.w, tb0.x, tb0.y, m0.y);
    ACC(sb0.z, sb0.w, sc0.x, tb0.z, tb0.w, tc0.x, m0.z);
    ACC(sc0.y, sc0.z, sc0.w, tc0.y, tc0.z, tc0.w, m0.w);
    ACC(sa1.x, sa1.y, sa1.z, ta1.x, ta1.y, ta1.z, m1.x);
    ACC(sa1.w, sb1.x, sb1.y, ta1.w, tb1.x, tb1.y, m1.y);
    ACC(sb1.z, sb1.w, sc1.x, tb1.z, tb1.w, tc1.x, m1.z);
    ACC(sc1.y, sc1.z, sc1.w, tc1.y, tc1.z, tc1.w, m1.w);

    // wave-64 butterfly reduction of the 9 accumulators
#pragma unroll
    for (int off = 32; off > 0; off >>= 1) {
#pragma unroll
        for (int i = 0; i < 9; ++i) h[i] += __shfl_down(h[i], off);
    }

    __shared__ float shred[THREADS / 64][9];
    const int wid  = t >> 6;
    const int lane = t & 63;
    if (lane == 0) {
#pragma unroll
        for (int i = 0; i < 9; ++i) shred[wid][i] = h[i];
    }
    __syncthreads();

    if (t != 0) return;

    // ---- Phase 2: single-thread fp64 Kabsch solve (all compile-time indexed) ----
    double H[3][3];
#pragma unroll
    for (int i = 0; i < 9; ++i)
        H[i / 3][i % 3] = (double)(shred[0][i] + shred[1][i] +
                                   shred[2][i] + shred[3][i]);

    double A[3][3];
#pragma unroll
    for (int i = 0; i < 3; ++i)
#pragma unroll
        for (int j = 0; j < 3; ++j)
            A[i][j] = H[0][i] * H[0][j] + H[1][i] * H[1][j] + H[2][i] * H[2][j];

    double V[3][3] = {{1, 0, 0}, {0, 1, 0}, {0, 0, 1}};

    for (int sweep = 0; sweep < 6; ++sweep) {
#pragma unroll
        for (int r = 0; r < 3; ++r) {
            // compile-time (p,q,k) per r: (0,1,2), (0,2,1), (1,2,0)
            const int p = (r == 2) ? 1 : 0;
            const int q = (r == 0) ? 1 : 2;
            const int k = (r == 0) ? 2 : ((r == 1) ? 1 : 0);
            double apq = A[p][q];
            if (fabs(apq) > 1e-300) {
                double theta = (A[q][q] - A[p][p]) / (2.0 * apq);
                double tt = 1.0 / (fabs(theta) + sqrt(theta * theta + 1.0));
                if (theta < 0.0) tt = -tt;
                double c = 1.0 / sqrt(tt * tt + 1.0);
                double s = tt * c;
                double app = A[p][p], aqq = A[q][q];
                A[p][p] = app - tt * apq;
                A[q][q] = aqq + tt * apq;
                A[p][q] = A[q][p] = 0.0;
                double akp = A[k][p], akq = A[k][q];
                A[k][p] = A[p][k] = c * akp - s * akq;
                A[k][q] = A[q][k] = s * akp + c * akq;
#pragma unroll
                for (int i = 0; i < 3; ++i) {
                    double vip = V[i][p], viq = V[i][q];
                    V[i][p] = c * vip - s * viq;
                    V[i][q] = s * vip + c * viq;
                }
            }
        }
    }

    // Branch-free eigen-column extraction: value selects only, no runtime
    // array indices. Matches the sequential argmax semantics of the original
    // (ties resolved identically except exact eigenvalue ties, which are
    // degenerate and handled by the downstream Gram-Schmidt anyway).
    const double d0 = A[0][0], d1 = A[1][1], d2 = A[2][2];
    const bool g01 = (d0 >= d1);
    const bool g02 = (d0 >= d2);
    const bool g12 = (d1 >= d2);
    const bool l0 = g01 && g02;        // column 0 is the largest
    const bool l1 = (!g01) && g12;     // column 1 is the largest

    double v0[3], v1[3];
#pragma unroll
    for (int i = 0; i < 3; ++i) {
        const double c0 = V[i][0], c1 = V[i][1], c2 = V[i][2];
        v0[i] = l0 ? c0 : (l1 ? c1 : c2);
        const double s_l0 = g12 ? c1 : c2;   // i0=0 -> i1 = d1>=d2 ? 1 : 2
        const double s_l1 = g02 ? c0 : c2;   // i0=1 -> i1 = d0>=d2 ? 0 : 2
        const double s_l2 = g01 ? c0 : c1;   // i0=2 -> i1 = d0>=d1 ? 0 : 1
        v1[i] = l0 ? s_l0 : (l1 ? s_l1 : s_l2);
    }

    double b0[3], b1[3];
#pragma unroll
    for (int r = 0; r < 3; ++r) {
        b0[r] = H[r][0] * v0[0] + H[r][1] * v0[1] + H[r][2] * v0[2];
        b1[r] = H[r][0] * v1[0] + H[r][1] * v1[1] + H[r][2] * v1[2];
    }
    double n0 = b0[0] * b0[0] + b0[1] * b0[1] + b0[2] * b0[2];
    double inv0 = 1.0 / sqrt(fmax(n0, 1e-300));
    double u0[3] = {b0[0] * inv0, b0[1] * inv0, b0[2] * inv0};
    double d01 = u0[0] * b1[0] + u0[1] * b1[1] + u0[2] * b1[2];
    double w[3] = {b1[0] - d01 * u0[0], b1[1] - d01 * u0[1], b1[2] - d01 * u0[2]};
    double nw = w[0] * w[0] + w[1] * w[1] + w[2] * w[2];
    double inv1 = 1.0 / sqrt(fmax(nw, 1e-300));
    double u1[3] = {w[0] * inv1, w[1] * inv1, w[2] * inv1};
    double u2[3] = {u0[1] * u1[2] - u0[2] * u1[1],
                    u0[2] * u1[0] - u0[0] * u1[2],
                    u0[0] * u1[1] - u0[1] * u1[0]};
    double vc2[3] = {v0[1] * v1[2] - v0[2] * v1[1],
                     v0[2] * v1[0] - v0[0] * v1[2],
                     v0[0] * v1[1] - v0[1] * v1[0]};

    float* o = out + (size_t)b * 9;
#pragma unroll
    for (int r = 0; r < 3; ++r)
#pragma unroll
        for (int c = 0; c < 3; ++c)
            o[r * 3 + c] = (float)(v0[r] * u0[c] + v1[r] * u1[c] + vc2[r] * u2[c]);
}

extern "C" void kernel_launch(void* const* d_in, const int* in_sizes, int n_in,
                              void* d_out, int out_size, void* d_ws, size_t ws_size,
                              hipStream_t stream) {
    const float* src  = (const float*)d_in[0];
    const float* tgt  = (const float*)d_in[1];
    // d_in[2] (kpt_src_mask) is unused by the reference
    const float* mask = (const float*)d_in[3];
    float* out = (float*)d_out;

    fused_kernel<<<BATCH, THREADS, 0, stream>>>(src, tgt, mask, out);
}